// Round 4
// baseline (967.202 us; speedup 1.0000x reference)
//
#include <hip/hip_runtime.h>

#define NN 100000
#define EE 600000
#define DD 164
#define HH 2
#define DKK 82
#define EDIM 16
#define TDIM 8
#define STEP 30000
#define NC 20          // EE / STEP
#define FEAT 24        // EDIM + TDIM
#define HID 82         // D/2
#define NG 41          // DD/4 float4 groups
#define KP 96          // padded K for MFMA (82 -> 96)
#define MP 336         // padded M (2*164 -> 336)
#define NBLK ((EE + 255) / 256)

typedef __attribute__((ext_vector_type(8))) short short8;
typedef __attribute__((ext_vector_type(4))) float floatx4;

__device__ __forceinline__ float fast_tanh(float x) {
    float e = __expf(2.0f * x);
    return 1.0f - 2.0f * __builtin_amdgcn_rcpf(e + 1.0f);
}

__device__ __forceinline__ short f2bf(float f) {
    union { float f; unsigned u; } x; x.f = f;
    unsigned r = x.u + 0x7fffu + ((x.u >> 16) & 1u);   // RNE
    return (short)(r >> 16);
}

__device__ __forceinline__ unsigned pack_f16(float g, float b) {
    union { _Float16 h[2]; unsigned u; } p;
    p.h[0] = (_Float16)g; p.h[1] = (_Float16)b;
    return p.u;
}

__device__ __forceinline__ float2 unpack_f16(unsigned x) {
    union { unsigned u; _Float16 h[2]; } p; p.u = x;
    return make_float2((float)p.h[0], (float)p.h[1]);
}

// ---------------- one-time weight prep: W2 -> pair-interleaved bf16, b2 -> permuted ----------------

__global__ void __launch_bounds__(256) prep_w2_kernel(
    const float* __restrict__ W2, const float* __restrict__ b2,
    short* __restrict__ W2p, float* __restrict__ b2p)
{
    int idx = blockIdx.x * 256 + threadIdx.x;
    if (idx < MP * KP) {
        int m = idx / KP, kk = idx - m * KP;
        float val = 0.f;
        if (m < 2 * DD && kk < HID) {
            int dth = m >> 1, p = m & 1;
            val = W2[(size_t)(dth + p * DD) * HID + kk];
        }
        W2p[idx] = f2bf(val);
    }
    if (idx < MP) {
        float bv = 0.f;
        if (idx < 2 * DD) { int dth = idx >> 1, p = idx & 1; bv = b2[dth + p * DD]; }
        b2p[idx] = bv;
    }
}

// ---------------- CSR build ----------------

__global__ void __launch_bounds__(256) zero2_kernel(int* __restrict__ a, int* __restrict__ b, int n) {
    int i = blockIdx.x * 256 + threadIdx.x;
    if (i < n) { a[i] = 0; b[i] = 0; }
}

__global__ void __launch_bounds__(256) count_kernel(const int* __restrict__ ei, int* __restrict__ deg) {
    int e = blockIdx.x * 256 + threadIdx.x;
    if (e < EE) atomicAdd(&deg[ei[EE + e]], 1);
}

__global__ void __launch_bounds__(256) scan_kernel(const int* __restrict__ deg, int* __restrict__ off) {
    const int CH = (NN + 255) / 256;
    int t = threadIdx.x;
    int beg = t * CH, end = min(beg + CH, NN);
    int s = 0;
    for (int i = beg; i < end; ++i) s += deg[i];
    __shared__ int sums[256];
    sums[t] = s;
    __syncthreads();
    for (int d = 1; d < 256; d <<= 1) {
        int val = (t >= d) ? sums[t - d] : 0;
        __syncthreads();
        sums[t] += val;
        __syncthreads();
    }
    int run = (t == 0) ? 0 : sums[t - 1];
    for (int i = beg; i < end; ++i) { off[i] = run; run += deg[i]; }
    if (t == 255) off[NN] = run;
}

// fill also records slot-ordered src node (srcp) when provided (tier-3 path)
__global__ void __launch_bounds__(256) fill_kernel(const int* __restrict__ ei,
                                                   const int* __restrict__ off,
                                                   int* __restrict__ cnt,
                                                   int* __restrict__ elist,
                                                   int* __restrict__ srcp) {
    int e = blockIdx.x * 256 + threadIdx.x;
    if (e >= EE) return;
    int d = ei[EE + e];
    int p = atomicAdd(&cnt[d], 1);
    int slot = off[d] + p;
    elist[slot] = e;
    if (srcp) srcp[slot] = ei[e];
}

// ---------------- score: 16-lane cooperative, coalesced row reads ----------------

__global__ void __launch_bounds__(256) score_coop_kernel(
    const float* __restrict__ q, const float* __restrict__ k,
    const int* __restrict__ ei, const float* __restrict__ rel_bias,
    const int* __restrict__ elist, float* __restrict__ escore)
{
    const int tid = threadIdx.x;
    const int grp = tid >> 4;          // 16 edge-groups per block
    const int gl  = tid & 15;
    int i = blockIdx.x * 16 + grp;     // dst-sorted edge slot
    if (i >= EE) return;
    int e = elist[i];
    int sn = ei[e];
    int dn = ei[EE + e];
    const float4* qr = (const float4*)(q + (size_t)dn * DD);
    const float4* kr = (const float4*)(k + (size_t)sn * DD);
    float s0 = 0.f, s1 = 0.f;
    #pragma unroll
    for (int jj = 0; jj < 3; ++jj) {
        int idx = gl + 16 * jj;
        if (idx < 41) {
            float4 a = qr[idx], b = kr[idx];
            float lo = a.x * b.x + a.y * b.y;
            float hi = a.z * b.z + a.w * b.w;
            s0 += (idx < 20 ? hi : 0.f) + (idx <= 20 ? lo : 0.f);
            s1 += (idx > 20 ? lo : 0.f) + (idx >= 20 ? hi : 0.f);
        }
    }
    #pragma unroll
    for (int m = 1; m < 16; m <<= 1) {
        s0 += __shfl_xor(s0, m, 64);
        s1 += __shfl_xor(s1, m, 64);
    }
    if (gl == 0) {
        const float inv_sqrt = 0.11043152607484654f;  // 1/sqrt(82)
        escore[2 * e]     = __expf(s0 * inv_sqrt + rel_bias[0]);
        escore[2 * e + 1] = __expf(s1 * inv_sqrt + rel_bias[1]);
    }
}

// original-order score for the fallback path
__global__ void __launch_bounds__(256) score_kernel(
    const float* __restrict__ q, const float* __restrict__ k,
    const int* __restrict__ ei, const float* __restrict__ rel_bias,
    float* __restrict__ escore)
{
    int e = blockIdx.x * 256 + threadIdx.x;
    if (e >= EE) return;
    int s = ei[e];
    int d = ei[EE + e];
    const float4* qr = (const float4*)(q + (size_t)d * DD);
    const float4* kr = (const float4*)(k + (size_t)s * DD);
    float s0 = 0.f, s1 = 0.f;
    #pragma unroll 4
    for (int i = 0; i < 20; ++i) {
        float4 a = qr[i], b = kr[i];
        s0 += a.x * b.x; s0 += a.y * b.y; s0 += a.z * b.z; s0 += a.w * b.w;
    }
    {
        float4 a = qr[20], b = kr[20];
        s0 += a.x * b.x + a.y * b.y;
        s1 += a.z * b.z + a.w * b.w;
    }
    #pragma unroll 4
    for (int i = 21; i < 41; ++i) {
        float4 a = qr[i], b = kr[i];
        s1 += a.x * b.x; s1 += a.y * b.y; s1 += a.z * b.z; s1 += a.w * b.w;
    }
    const float inv_sqrt = 0.11043152607484654f;  // 1/sqrt(82)
    escore[2 * e]     = __expf(s0 * inv_sqrt + rel_bias[0]);
    escore[2 * e + 1] = __expf(s1 * inv_sqrt + rel_bias[1]);
}

__global__ void __launch_bounds__(256) chunkinv_kernel(
    const float* __restrict__ escore, float* __restrict__ invsum)
{
    int c = blockIdx.x, h = blockIdx.y;
    const float* base = escore + (size_t)c * STEP * 2 + h;
    float acc = 0.f;
    for (int i = threadIdx.x; i < STEP; i += 256) acc += base[2 * i];
    __shared__ float red[256];
    red[threadIdx.x] = acc;
    __syncthreads();
    for (int s2 = 128; s2 > 0; s2 >>= 1) {
        if (threadIdx.x < s2) red[threadIdx.x] += red[threadIdx.x + s2];
        __syncthreads();
    }
    if (threadIdx.x == 0) invsum[c * 2 + h] = 1.0f / red[0];
}

__global__ void __launch_bounds__(256) zero_kernel(float4* __restrict__ p, int n4) {
    int i = blockIdx.x * 256 + threadIdx.x;
    if (i < n4) p[i] = make_float4(0.f, 0.f, 0.f, 0.f);
}

// ---------------- Tier-3 kernel A: staging + W2 GEMM + tanh -> gbp (f16 pairs), attp ----
// One barrier total. No v-gather, no leader logic, no res_lds. LDS = 48 KB -> 3 blocks/CU.
// gbp[slot][dim] = packed (f16 gamma, f16 beta), slot = dst-sorted edge order.

__global__ void __launch_bounds__(256) gemm_film_kernel(
    const int* __restrict__ ei,
    const float* __restrict__ edge_attr, const float* __restrict__ edge_time,
    const float* __restrict__ Wt, const float* __restrict__ bt,
    const float* __restrict__ W1, const float* __restrict__ b1,
    const short* __restrict__ W2p, const float* __restrict__ b2p,
    const float* __restrict__ escore, const float* __restrict__ invsum,
    const int* __restrict__ elist,
    unsigned* __restrict__ gbp, float* __restrict__ attp)
{
    __shared__ short hmid_lds[256 * KP];   // 48 KB

    const int tid = threadIdx.x;
    const int bs  = blockIdx.x * 256;
    const int gid = bs + tid;
    const bool valid = gid < EE;
    const int gi = valid ? gid : (EE - 1);
    const int e = elist[gi];
    if (valid) {
        unsigned c = (unsigned)e / STEP;
        attp[2 * gid]     = escore[2 * e]     * invsum[2 * c];
        attp[2 * gid + 1] = escore[2 * e + 1] * invsum[2 * c + 1];
    }

    // ---- feat ----
    float feat[FEAT];
    const float4* ea4 = (const float4*)(edge_attr + (size_t)e * EDIM);
    #pragma unroll
    for (int i = 0; i < 4; ++i) {
        float4 a = ea4[i];
        feat[4 * i + 0] = a.x; feat[4 * i + 1] = a.y;
        feat[4 * i + 2] = a.z; feat[4 * i + 3] = a.w;
    }
    float t = edge_time[e];
    #pragma unroll
    for (int j = 0; j < TDIM; ++j) feat[EDIM + j] = t * Wt[j] + bt[j];

    // ---- hmid in 8-wide chunks -> bf16 -> LDS ----
    #pragma unroll 1
    for (int oc = 0; oc < KP / 8; ++oc) {
        union { short h[8]; int4 v4; } pk;
        #pragma unroll
        for (int j = 0; j < 8; ++j) {
            int o = oc * 8 + j;
            float acc = 0.f;
            if (o < HID) {
                acc = b1[o];
                #pragma unroll
                for (int f = 0; f < FEAT; ++f) acc = fmaf(feat[f], W1[o * FEAT + f], acc);
                acc = fmaxf(acc, 0.f);
            }
            pk.h[j] = f2bf(acc);
        }
        *(int4*)&hmid_lds[tid * KP + oc * 8] = pk.v4;
    }
    __syncthreads();

    const int lane = tid & 63;
    const int wavebase = tid & ~63;
    const int lrow = lane & 15;
    const int quad = lane >> 4;

    // ---- B fragments: persistent across the whole mt loop ----
    short8 bfrag[4][3];
    #pragma unroll
    for (int nt = 0; nt < 4; ++nt)
        #pragma unroll
        for (int ks = 0; ks < 3; ++ks)
            bfrag[nt][ks] = *(const short8*)&hmid_lds[(wavebase + nt * 16 + lrow) * KP + ks * 32 + quad * 8];

    #pragma unroll 1
    for (int mt = 0; mt < 21; ++mt) {
        short8 afrag[3];
        #pragma unroll
        for (int ks = 0; ks < 3; ++ks)
            afrag[ks] = *(const short8*)&W2p[(mt * 16 + lrow) * KP + ks * 32 + quad * 8];

        floatx4 acc[4];
        #pragma unroll
        for (int nt = 0; nt < 4; ++nt) acc[nt] = (floatx4)(0.f);
        #pragma unroll
        for (int ks = 0; ks < 3; ++ks)
            #pragma unroll
            for (int nt = 0; nt < 4; ++nt)
                acc[nt] = __builtin_amdgcn_mfma_f32_16x16x32_bf16(afrag[ks], bfrag[nt][ks], acc[nt], 0, 0, 0);

        float4 bias = *(const float4*)&b2p[mt * 16 + quad * 4];
        int d0 = mt * 8 + quad * 2;

        if (d0 < DD) {
            #pragma unroll
            for (int nt = 0; nt < 4; ++nt) {
                int e_loc = wavebase + nt * 16 + lrow;
                int slot = bs + e_loc;
                if (slot < EE) {
                    float g0  = fast_tanh(acc[nt][0] + bias.x);
                    float be0 = fast_tanh(acc[nt][1] + bias.y);
                    float g1  = fast_tanh(acc[nt][2] + bias.z);
                    float be1 = fast_tanh(acc[nt][3] + bias.w);
                    uint2 pk;
                    pk.x = pack_f16(g0, be0);
                    pk.y = pack_f16(g1, be1);
                    *(uint2*)&gbp[(size_t)slot * DD + d0] = pk;
                }
            }
        }
    }
}

// ---------------- Tier-3 kernel B: per-node segment reduce, fully coalesced ----
// One wave per dst node. Lane l owns dims {l, l+64, l+128}. Streams gbp (slot-contiguous),
// reads v rows whole (coalesced 656 B), writes out rows directly. No atomics/barriers/LDS.

__global__ void __launch_bounds__(256) reduce_kernel(
    const float* __restrict__ v, const int* __restrict__ off,
    const int* __restrict__ srcp, const float* __restrict__ attp,
    const unsigned* __restrict__ gbp, float* __restrict__ out)
{
    int gw   = (blockIdx.x * 256 + threadIdx.x) >> 6;
    int lane = threadIdx.x & 63;
    if (gw >= NN) return;
    int beg = off[gw], end = off[gw + 1];

    const int d1 = lane + 64;
    const int d2 = lane + 128;
    const bool has2 = (d2 < DD);           // lane < 36
    float acc0 = 0.f, acc1 = 0.f, acc2 = 0.f;

    for (int sl = beg; sl < end; ++sl) {
        int src = srcp[sl];                 // wave-uniform
        float t0 = attp[2 * sl];            // wave-uniform
        float t1 = attp[2 * sl + 1];
        const float*    vr = v   + (size_t)src * DD;
        const unsigned* gr = gbp + (size_t)sl  * DD;

        unsigned g0 = gr[lane], g1 = gr[d1];
        float    v0 = vr[lane], v1 = vr[d1];
        float2 gb0 = unpack_f16(g0);
        float2 gb1 = unpack_f16(g1);
        acc0 += t0 * (v0 * (1.f + gb0.x) + gb0.y);                    // dims 0..63: head0
        float ts = (d1 < DKK) ? t0 : t1;                               // head split at 82
        acc1 += ts * (v1 * (1.f + gb1.x) + gb1.y);
        if (has2) {
            unsigned g2 = gr[d2];
            float    v2 = vr[d2];
            float2 gb2 = unpack_f16(g2);
            acc2 += t1 * (v2 * (1.f + gb2.x) + gb2.y);                 // dims 128..163: head1
        }
    }
    float* orow = out + (size_t)gw * DD;
    orow[lane] = acc0;
    orow[d1]   = acc1;
    if (has2) orow[d2] = acc2;
}

// ---------------- Tier-2 main: round-1 proven structure (447 us) ----------------

__global__ void __launch_bounds__(256) main_mfma_kernel(
    const float* __restrict__ v, const int* __restrict__ ei,
    const float* __restrict__ edge_attr, const float* __restrict__ edge_time,
    const float* __restrict__ Wt, const float* __restrict__ bt,
    const float* __restrict__ W1, const float* __restrict__ b1,
    const short* __restrict__ W2p, const float* __restrict__ b2p,
    const float* __restrict__ escore, const float* __restrict__ invsum,
    const int* __restrict__ off, const int* __restrict__ elist,
    float* __restrict__ out)
{
    __shared__ short hmid_lds[256 * KP];
    __shared__ float res_lds[256 * 8];
    __shared__ int   sdst[256];
    __shared__ int   ssrc[256];
    __shared__ float satt[512];

    const int tid = threadIdx.x;
    const int gid = blockIdx.x * 256 + tid;
    const bool valid = gid < EE;
    const int gi = valid ? gid : (EE - 1);
    const int e = elist[gi];
    const int s = ei[e];
    const int d = ei[EE + e];
    sdst[tid] = valid ? d : -1;
    ssrc[tid] = s;
    {
        unsigned c = (unsigned)e / STEP;
        satt[2 * tid]     = escore[2 * e]     * invsum[2 * c];
        satt[2 * tid + 1] = escore[2 * e + 1] * invsum[2 * c + 1];
    }

    float feat[FEAT];
    const float4* ea4 = (const float4*)(edge_attr + (size_t)e * EDIM);
    #pragma unroll
    for (int i = 0; i < 4; ++i) {
        float4 a = ea4[i];
        feat[4 * i + 0] = a.x; feat[4 * i + 1] = a.y;
        feat[4 * i + 2] = a.z; feat[4 * i + 3] = a.w;
    }
    float t = edge_time[e];
    #pragma unroll
    for (int j = 0; j < TDIM; ++j) feat[EDIM + j] = t * Wt[j] + bt[j];

    #pragma unroll 1
    for (int oc = 0; oc < KP / 8; ++oc) {
        union { short h[8]; int4 v4; } pk;
        #pragma unroll
        for (int j = 0; j < 8; ++j) {
            int o = oc * 8 + j;
            float acc = 0.f;
            if (o < HID) {
                acc = b1[o];
                #pragma unroll
                for (int f = 0; f < FEAT; ++f) acc = fmaf(feat[f], W1[o * FEAT + f], acc);
                acc = fmaxf(acc, 0.f);
            }
            pk.h[j] = f2bf(acc);
        }
        *(int4*)&hmid_lds[tid * KP + oc * 8] = pk.v4;
    }
    __syncthreads();

    const int lane = tid & 63;
    const int wavebase = tid & ~63;
    const int lrow = lane & 15;
    const int quad = lane >> 4;

    short8 bfrag[4][3];
    #pragma unroll
    for (int nt = 0; nt < 4; ++nt)
        #pragma unroll
        for (int ks = 0; ks < 3; ++ks)
            bfrag[nt][ks] = *(const short8*)&hmid_lds[(wavebase + nt * 16 + lrow) * KP + ks * 32 + quad * 8];

    bool leader = valid && (tid == 0 || sdst[tid - 1] != d);
    int seglen = 0;
    bool interior = false;
    float* orow = nullptr;
    if (leader) {
        while (tid + seglen < 256 && sdst[tid + seglen] == d) ++seglen;
        int bs = blockIdx.x * 256;
        interior = (off[d] >= bs) && (off[d + 1] <= bs + 256);
        orow = out + (size_t)d * DD;
    }

    #pragma unroll 1
    for (int mt = 0; mt < 21; ++mt) {
        short8 afrag[3];
        #pragma unroll
        for (int ks = 0; ks < 3; ++ks)
            afrag[ks] = *(const short8*)&W2p[(mt * 16 + lrow) * KP + ks * 32 + quad * 8];

        floatx4 acc[4];
        #pragma unroll
        for (int nt = 0; nt < 4; ++nt) acc[nt] = (floatx4)(0.f);
        #pragma unroll
        for (int ks = 0; ks < 3; ++ks)
            #pragma unroll
            for (int nt = 0; nt < 4; ++nt)
                acc[nt] = __builtin_amdgcn_mfma_f32_16x16x32_bf16(afrag[ks], bfrag[nt][ks], acc[nt], 0, 0, 0);

        float4 bias = *(const float4*)&b2p[mt * 16 + quad * 4];
        int d0 = mt * 8 + quad * 2;

        #pragma unroll
        for (int nt = 0; nt < 4; ++nt) {
            int e_loc = wavebase + nt * 16 + lrow;
            float r0 = 0.f, r1 = 0.f;
            if (d0 < DD) {
                float g0  = fast_tanh(acc[nt][0] + bias.x);
                float be0 = fast_tanh(acc[nt][1] + bias.y);
                float g1  = fast_tanh(acc[nt][2] + bias.z);
                float be1 = fast_tanh(acc[nt][3] + bias.w);
                int s_e = ssrc[e_loc];
                const float* vp = v + (size_t)s_e * DD + d0;
                float v0 = vp[0], v1 = vp[1];
                float a0 = satt[2 * e_loc + (d0 >= DKK ? 1 : 0)];
                float a1 = satt[2 * e_loc + (d0 + 1 >= DKK ? 1 : 0)];
                r0 = a0 * (v0 * (1.f + g0) + be0);
                r1 = a1 * (v1 * (1.f + g1) + be1);
            }
            res_lds[e_loc * 8 + quad * 2]     = r0;
            res_lds[e_loc * 8 + quad * 2 + 1] = r1;
        }
        __syncthreads();

        if (leader) {
            float4 s0 = make_float4(0.f, 0.f, 0.f, 0.f);
            float4 s1 = make_float4(0.f, 0.f, 0.f, 0.f);
            for (int t2 = 0; t2 < seglen; ++t2) {
                const float4* rp = (const float4*)&res_lds[(tid + t2) * 8];
                float4 a = rp[0], b = rp[1];
                s0.x += a.x; s0.y += a.y; s0.z += a.z; s0.w += a.w;
                s1.x += b.x; s1.y += b.y; s1.z += b.z; s1.w += b.w;
            }
            int D0 = mt * 8;
            if (interior) {
                *(float4*)(orow + D0) = s0;
                if (D0 + 4 < DD) *(float4*)(orow + D0 + 4) = s1;
            } else {
                unsafeAtomicAdd(orow + D0 + 0, s0.x);
                unsafeAtomicAdd(orow + D0 + 1, s0.y);
                unsafeAtomicAdd(orow + D0 + 2, s0.z);
                unsafeAtomicAdd(orow + D0 + 3, s0.w);
                if (D0 + 4 < DD) {
                    unsafeAtomicAdd(orow + D0 + 4, s1.x);
                    unsafeAtomicAdd(orow + D0 + 5, s1.y);
                    unsafeAtomicAdd(orow + D0 + 6, s1.z);
                    unsafeAtomicAdd(orow + D0 + 7, s1.w);
                }
            }
        }
        __syncthreads();
    }
}

// ---------------- Tier-1 fallback (proved-correct atomic path) ----------------

__global__ void __launch_bounds__(256) main_atomic_kernel(
    const float* __restrict__ v, const int* __restrict__ ei,
    const float* __restrict__ edge_attr, const float* __restrict__ edge_time,
    const float* __restrict__ Wt, const float* __restrict__ bt,
    const float* __restrict__ W1, const float* __restrict__ b1,
    const float* __restrict__ W2, const float* __restrict__ b2,
    const float* __restrict__ escore, const float* __restrict__ invsum,
    float* __restrict__ out)
{
    int e = blockIdx.x * 256 + threadIdx.x;
    if (e >= EE) return;
    int s = ei[e];
    int d = ei[EE + e];
    float feat[FEAT];
    const float4* ea4 = (const float4*)(edge_attr + (size_t)e * EDIM);
    #pragma unroll
    for (int i = 0; i < 4; ++i) {
        float4 a = ea4[i];
        feat[4 * i + 0] = a.x; feat[4 * i + 1] = a.y;
        feat[4 * i + 2] = a.z; feat[4 * i + 3] = a.w;
    }
    float t = edge_time[e];
    #pragma unroll
    for (int j = 0; j < TDIM; ++j) feat[EDIM + j] = t * Wt[j] + bt[j];
    float hmid[HID];
    #pragma unroll
    for (int o = 0; o < HID; ++o) {
        float acc = b1[o];
        #pragma unroll
        for (int f = 0; f < FEAT; ++f) acc = fmaf(feat[f], W1[o * FEAT + f], acc);
        hmid[o] = fmaxf(acc, 0.f);
    }
    int c = e / STEP;
    float att0 = escore[2 * e]     * invsum[2 * c];
    float att1 = escore[2 * e + 1] * invsum[2 * c + 1];
    const float4* vrow4 = (const float4*)(v + (size_t)s * DD);
    float* orow = out + (size_t)d * DD;
    #pragma unroll 1
    for (int j = 0; j < NG; ++j) {
        float4 vv = vrow4[j];
        float vvals[4] = {vv.x, vv.y, vv.z, vv.w};
        float res[4];
        #pragma unroll
        for (int u = 0; u < 4; ++u) {
            int dd = 4 * j + u;
            float ga = b2[dd];
            float bb = b2[dd + DD];
            #pragma unroll
            for (int o = 0; o < HID; ++o) {
                ga = fmaf(hmid[o], W2[dd * HID + o], ga);
                bb = fmaf(hmid[o], W2[(dd + DD) * HID + o], bb);
            }
            float gamma = fast_tanh(ga);
            float beta  = fast_tanh(bb);
            float vh = vvals[u] * (1.f + gamma) + beta;
            res[u] = ((dd < DKK) ? att0 : att1) * vh;
        }
        unsafeAtomicAdd(orow + 4 * j + 0, res[0]);
        unsafeAtomicAdd(orow + 4 * j + 1, res[1]);
        unsafeAtomicAdd(orow + 4 * j + 2, res[2]);
        unsafeAtomicAdd(orow + 4 * j + 3, res[3]);
    }
}

// ---------------- launch ----------------

extern "C" void kernel_launch(void* const* d_in, const int* in_sizes, int n_in,
                              void* d_out, int out_size, void* d_ws, size_t ws_size,
                              hipStream_t stream) {
    const float* q   = (const float*)d_in[0];
    const float* k   = (const float*)d_in[1];
    const float* v   = (const float*)d_in[2];
    const int*   ei  = (const int*)d_in[3];
    const float* ea  = (const float*)d_in[4];
    const float* et  = (const float*)d_in[5];
    const float* Wt  = (const float*)d_in[6];
    const float* bt  = (const float*)d_in[7];
    const float* W1  = (const float*)d_in[8];
    const float* b1  = (const float*)d_in[9];
    const float* W2  = (const float*)d_in[10];
    const float* b2  = (const float*)d_in[11];
    const float* rb  = (const float*)d_in[12];
    float* out = (float*)d_out;

    // Tier-2 layout (legacy, ~9.8 MB)
    size_t need2 = (size_t)(MP * KP) * 2 + (MP + 2 * EE + 64) * 4 +
                   ((size_t)3 * NN + 1 + EE) * 4;
    // Tier-3 layout: gbp first (16B-aligned block), then everything else
    size_t need3 = (size_t)EE * DD * 4                    // gbp
                 + (size_t)(MP * KP) * 2 + (MP + 2 * EE + 64) * 4
                 + ((size_t)3 * NN + 1) * 4
                 + (size_t)EE * 4                         // elist
                 + (size_t)EE * 4                         // srcp
                 + (size_t)2 * EE * 4;                    // attp

    if (ws_size >= need3) {
        unsigned* gbp  = (unsigned*)d_ws;                 // EE*DD
        short* W2p     = (short*)(gbp + (size_t)EE * DD); // 64512 B
        float* b2p     = (float*)(W2p + MP * KP);         // 1344 B
        float* escore  = b2p + MP;                        // 2*EE
        float* invsum  = escore + (size_t)2 * EE;         // 64
        int*   deg     = (int*)(invsum + 64);             // NN
        int*   off     = deg + NN;                        // NN+1
        int*   cnt     = off + NN + 1;                    // NN
        int*   elist   = cnt + NN;                        // EE
        int*   srcp    = elist + EE;                      // EE
        float* attp    = (float*)(srcp + EE);             // 2*EE

        prep_w2_kernel<<<(MP * KP + 255) / 256, 256, 0, stream>>>(W2, b2, W2p, b2p);
        zero2_kernel<<<(NN + 255) / 256, 256, 0, stream>>>(deg, cnt, NN);
        count_kernel<<<NBLK, 256, 0, stream>>>(ei, deg);
        scan_kernel<<<1, 256, 0, stream>>>(deg, off);
        fill_kernel<<<NBLK, 256, 0, stream>>>(ei, off, cnt, elist, srcp);
        score_coop_kernel<<<(EE + 15) / 16, 256, 0, stream>>>(q, k, ei, rb, elist, escore);
        chunkinv_kernel<<<dim3(NC, HH), 256, 0, stream>>>(escore, invsum);
        gemm_film_kernel<<<NBLK, 256, 0, stream>>>(
            ei, ea, et, Wt, bt, W1, b1, W2p, b2p, escore, invsum, elist, gbp, attp);
        // one wave per node; out fully written (zeros for empty nodes), no zero pass needed
        reduce_kernel<<<(NN * 64 + 255) / 256, 256, 0, stream>>>(
            v, off, srcp, attp, gbp, out);
    } else if (ws_size >= need2) {
        short* W2p    = (short*)d_ws;
        float* b2p    = (float*)(W2p + MP * KP);
        float* escore = b2p + MP;
        float* invsum = escore + (size_t)2 * EE;
        int*   deg    = (int*)(invsum + 64);
        int*   off    = deg + NN;
        int*   cnt    = off + NN + 1;
        int*   elist  = cnt + NN;

        int n4 = out_size / 4;
        zero_kernel<<<(n4 + 255) / 256, 256, 0, stream>>>((float4*)out, n4);
        prep_w2_kernel<<<(MP * KP + 255) / 256, 256, 0, stream>>>(W2, b2, W2p, b2p);
        zero2_kernel<<<(NN + 255) / 256, 256, 0, stream>>>(deg, cnt, NN);
        count_kernel<<<NBLK, 256, 0, stream>>>(ei, deg);
        scan_kernel<<<1, 256, 0, stream>>>(deg, off);
        fill_kernel<<<NBLK, 256, 0, stream>>>(ei, off, cnt, elist, (int*)nullptr);
        score_coop_kernel<<<(EE + 15) / 16, 256, 0, stream>>>(q, k, ei, rb, elist, escore);
        chunkinv_kernel<<<dim3(NC, HH), 256, 0, stream>>>(escore, invsum);
        main_mfma_kernel<<<NBLK, 256, 0, stream>>>(
            v, ei, ea, et, Wt, bt, W1, b1, W2p, b2p, escore, invsum, off, elist, out);
    } else {
        float* escore_f = (float*)d_ws;
        float* invsum_f = escore_f + (size_t)2 * EE;
        int n4 = out_size / 4;
        zero_kernel<<<(n4 + 255) / 256, 256, 0, stream>>>((float4*)out, n4);
        score_kernel<<<NBLK, 256, 0, stream>>>(q, k, ei, rb, escore_f);
        chunkinv_kernel<<<dim3(NC, HH), 256, 0, stream>>>(escore_f, invsum_f);
        main_atomic_kernel<<<NBLK, 256, 0, stream>>>(
            v, ei, ea, et, Wt, bt, W1, b1, W2, b2, escore_f, invsum_f, out);
    }
}